// Round 7
// baseline (2799.216 us; speedup 1.0000x reference)
//
#include <hip/hip_runtime.h>

// ---------------------------------------------------------------------------
// CausalityScoreModule: B=8, N=4096, D=128, K=256
// R6: f32 EMULATION of the reference's own arithmetic (golden = jax/np f32
// output; exact-f64 ordering provably differs at near-tie ranks -> R3/R4/R5
// identical failures). V0 world-model of XLA-CPU lowering:
//   mean: sequential over n, *(1/4096) (exact pow2)
//   var:  sequential over d, mul+add (no fma), sqrtf, +1e-6f
//   y:    8-lane stride-8 fma chains over d + predux tree (Eigen MatVec)
//   cov:  sequential-d scalar FMA chain (Eigen gemm micro-kernel)
//   A:    fabsf(g / (v_n * v_m))
//   rowsum: per-lane chains (order negligible at flip scale)
//   d:    1.0f/sqrtf(rowsum)   (XLA pow(x,-0.5) -> rsqrt)
//   S:    Eigen MatVec: acc_j (j=m mod 8) fma chains ascending;
//         e_i = acc_i+acc_{i+4}; S = (e0+e2)+(e1+e3)
// All mul/add kept un-contracted (#pragma clang fp contract(off)).
// ---------------------------------------------------------------------------

#define NN 4096
#define DD 128
#define KK 256

// --- mean over n (sequential chain per (b,d)) -------------------------------
__global__ __launch_bounds__(128) void k_mean(
    const float* __restrict__ X, float* __restrict__ mean) {
#pragma clang fp contract(off)
  int b = blockIdx.x, d = threadIdx.x;
  const float* p = X + (size_t)b * NN * DD + d;
  float acc = 0.f;
#pragma unroll 8
  for (int n = 0; n < NN; ++n) acc = acc + p[(size_t)n * DD];
  mean[b * DD + d] = acc * (1.0f / 4096.0f);
}

// --- per-row: Xc store, var (seq-d mul-add), y (8-chain fma + predux) -------
__global__ __launch_bounds__(256) void k_rows(
    const float* __restrict__ X, const float* __restrict__ W,
    const float* __restrict__ mean, float* __restrict__ Xc,
    float* __restrict__ vvec, float* __restrict__ yvec) {
#pragma clang fp contract(off)
  __shared__ float wL[DD], mL[DD];
  int t = threadIdx.x;
  int b = blockIdx.x >> 4;            // 16 blocks of 256 rows per batch
  if (t < DD) { wL[t] = W[t]; mL[t] = mean[b * DD + t]; }
  __syncthreads();
  int rg = blockIdx.x * 256 + t;      // global row [0, 32768)
  const float* xp = X + (size_t)rg * DD;
  float* xcp = Xc + (size_t)rg * DD;
  float xc[DD];
  float x[DD];
#pragma unroll
  for (int i = 0; i < 32; ++i) {
    float4 v4 = *(const float4*)(xp + i * 4);
    x[i*4] = v4.x; x[i*4+1] = v4.y; x[i*4+2] = v4.z; x[i*4+3] = v4.w;
  }
#pragma unroll
  for (int d = 0; d < DD; ++d) xc[d] = x[d] - mL[d];
#pragma unroll
  for (int i = 0; i < 32; ++i) {
    float4 v4; v4.x = xc[i*4]; v4.y = xc[i*4+1]; v4.z = xc[i*4+2]; v4.w = xc[i*4+3];
    *(float4*)(xcp + i * 4) = v4;
  }
  // var: sequential d, mul then add (no contraction)
  float vs = 0.f;
#pragma unroll
  for (int d = 0; d < DD; ++d) {
    float p = xc[d] * xc[d];
    vs = vs + p;
  }
  vvec[rg] = sqrtf(vs) + 1e-6f;
  // y: 8 fma chains over d (stride 8), predux tree
  float ay[8] = {0.f,0.f,0.f,0.f,0.f,0.f,0.f,0.f};
#pragma unroll
  for (int d = 0; d < DD; ++d)
    ay[d & 7] = __builtin_fmaf(x[d], wL[d], ay[d & 7]);
  float e0 = ay[0] + ay[4], e1 = ay[1] + ay[5];
  float e2 = ay[2] + ay[6], e3 = ay[3] + ay[7];
  yvec[rg] = (e0 + e2) + (e1 + e3);
}

// --- gram passes ------------------------------------------------------------
// Block: 32 n-rows x 8 m-phase lanes (thread t: nl=t>>3, j=t&7).
// Thread's chain j covers m = j, j+8, j+16, ... ascending (Eigen MatVec acc_j).
// PASS 0: rowsum chains (plain add). PASS 1: S chains (fma with A_norm*y).
template <int PASS>
__global__ __launch_bounds__(256) void k_gram(
    const float* __restrict__ Xc, const float* __restrict__ vvec,
    const float* __restrict__ dvec, const float* __restrict__ yvec,
    float* __restrict__ outv) {
#pragma clang fp contract(off)
  __shared__ float Xm[128][132];
  __shared__ float vmL[128], dmL[128], wmL[128];
  __shared__ float red[32][8];
  int bid = blockIdx.x;
  int b = bid & 7;                    // batch -> XCD round robin
  int n0 = (bid >> 3) * 32;
  int t = threadIdx.x;
  int nl = t >> 3, j = t & 7;
  size_t base = (size_t)b * NN * DD;
  int ng = n0 + nl;

  float xcn[DD];
  {
    const float4* src = (const float4*)(Xc + base + (size_t)ng * DD);
#pragma unroll
    for (int i = 0; i < 32; ++i) {
      float4 v4 = src[i];
      xcn[i*4] = v4.x; xcn[i*4+1] = v4.y; xcn[i*4+2] = v4.z; xcn[i*4+3] = v4.w;
    }
  }
  float vn = vvec[b * NN + ng];
  float dn = (PASS == 1) ? dvec[b * NN + ng] : 0.f;
  float acc = 0.f;

  for (int mt = 0; mt < 32; ++mt) {
    __syncthreads();
#pragma unroll
    for (int i = 0; i < 16; ++i) {    // stage 128x128 f32 tile (padded 132)
      int e = t + i * 256;
      int r = e >> 5, c = e & 31;
      float4 v4 = *(const float4*)(Xc + base + (size_t)(mt * 128 + r) * DD + c * 4);
      Xm[r][c*4] = v4.x; Xm[r][c*4+1] = v4.y; Xm[r][c*4+2] = v4.z; Xm[r][c*4+3] = v4.w;
    }
    if (t < 128) {
      vmL[t] = vvec[b * NN + mt * 128 + t];
      if (PASS == 1) {
        dmL[t] = dvec[b * NN + mt * 128 + t];
        wmL[t] = yvec[b * NN + mt * 128 + t];
      }
    }
    __syncthreads();
#pragma unroll 1
    for (int k = 0; k < 16; ++k) {
      int r = k * 8 + j;              // this lane's m within tile
      // cov: sequential-d scalar FMA chain (order d ascending)
      float g = 0.f;
      const float* xm = &Xm[r][0];
#pragma unroll
      for (int d = 0; d < DD; ++d) g = __builtin_fmaf(xcn[d], xm[d], g);
      float A = fabsf(g / (vn * vmL[r]));
      if (PASS == 0) {
        acc = acc + A;
      } else {
        float t2 = (dn * A) * dmL[r]; // (d_n * A) * d_m, two roundings
        acc = __builtin_fmaf(t2, wmL[r], acc);
      }
    }
  }
  __syncthreads();
  red[nl][j] = acc;
  __syncthreads();
  if (t < 32) {                       // predux: (a0+a4),(a2+a6)... tree
    float r0 = red[t][0], r1 = red[t][1], r2 = red[t][2], r3 = red[t][3];
    float r4 = red[t][4], r5 = red[t][5], r6 = red[t][6], r7 = red[t][7];
    float e0 = r0 + r4, e1 = r1 + r5, e2 = r2 + r6, e3 = r3 + r7;
    outv[b * NN + n0 + t] = (e0 + e2) + (e1 + e3);
  }
}

// --- d = rowsum ** -0.5  (XLA: rsqrt -> 1/sqrt) -----------------------------
__global__ __launch_bounds__(256) void k_d(
    const float* __restrict__ rows, float* __restrict__ dvec) {
#pragma clang fp contract(off)
  int i = blockIdx.x * 256 + threadIdx.x;
  dvec[i] = 1.0f / sqrtf(rows[i]);
}

// --- exact top-256 by rank-counting on f32 S (ties -> smaller index) --------
__global__ __launch_bounds__(256) void k_rank(
    const float* __restrict__ S, int* __restrict__ tkf) {
  __shared__ float sv[NN];
  int b = blockIdx.x >> 4, chunk = blockIdx.x & 15, t = threadIdx.x;
  const float* Sb = S + (size_t)b * NN;
#pragma unroll
  for (int jj = 0; jj < 16; ++jj) sv[t + jj * 256] = Sb[t + jj * 256];
  __syncthreads();
  int n = chunk * 256 + t;
  float s = sv[n];
  int cnt = 0;
  for (int m = 0; m < NN; ++m) {
    float x = sv[m];
    cnt += (x > s) || (x == s && m < n);
  }
  if (cnt < KK) tkf[b * KK + cnt] = n;
}

// --- gather F_c rows --------------------------------------------------------
__global__ __launch_bounds__(256) void k_gather(
    const float* __restrict__ X, const int* __restrict__ tkf,
    float* __restrict__ Fc) {
  int wid = threadIdx.x >> 6, lane = threadIdx.x & 63;
  int rid = blockIdx.x * 4 + wid;     // [0, 2048)
  int b = rid >> 8;
  int idx = tkf[rid];
  ((float2*)Fc)[(size_t)rid * 64 + lane] =
      ((const float2*)X)[((size_t)b * NN + idx) * 64 + lane];
}

// --- means (thresholds generous; internal f64; colsum = mean*4096 exact) ----
__global__ __launch_bounds__(128) void k_means_out(
    const float* __restrict__ X, const int* __restrict__ tkf,
    const float* __restrict__ mean, float* __restrict__ FcMean,
    float* __restrict__ FncMean) {
  int b = blockIdx.x, d = threadIdx.x;
  double s = 0.0;
  for (int k = 0; k < KK; ++k) {
    int idx = tkf[b * KK + k];
    s += (double)X[((size_t)b * NN + idx) * DD + d];
  }
  FcMean[b * DD + d] = (float)(s * (1.0 / 256.0));
  double colsum = (double)mean[b * DD + d] * 4096.0;  // exact (pow2 scale)
  FncMean[b * DD + d] = (float)((colsum - s) * (1.0 / 3840.0));
}

// ---------------------------------------------------------------------------
extern "C" void kernel_launch(void* const* d_in, const int* in_sizes, int n_in,
                              void* d_out, int out_size, void* d_ws,
                              size_t ws_size, hipStream_t stream) {
  (void)in_sizes; (void)n_in; (void)out_size; (void)ws_size;
  const float* X = (const float*)d_in[0];
  const float* W = (const float*)d_in[1];
  float* out = (float*)d_out;
  char* ws = (char*)d_ws;

  // workspace layout (bytes), total ~17.3 MB
  float* mean = (float*)(ws + 0);                 //   4 KB (8x128)
  float* Xc   = (float*)(ws + 4096);              //  16 MB
  float* vv   = (float*)(ws + 4096 + 16777216);   // 128 KB
  float* yv   = (float*)(ws + 16912384);          // 128 KB
  float* rows = (float*)(ws + 17043456);          // 128 KB
  float* dv   = (float*)(ws + 17174528);          // 128 KB
  int*   tkf  = (int*)(ws + 17305600);            //   8 KB

  float* S_out   = out;                 // [8,4096]
  float* Fc      = out + 32768;         // [8,256,128]
  float* FcMean  = out + 32768 + 262144;
  float* FncMean = FcMean + 1024;

  k_mean<<<8, 128, 0, stream>>>(X, mean);
  k_rows<<<128, 256, 0, stream>>>(X, W, mean, Xc, vv, yv);
  k_gram<0><<<1024, 256, 0, stream>>>(Xc, vv, dv, yv, rows);   // rowsums
  k_d<<<128, 256, 0, stream>>>(rows, dv);
  k_gram<1><<<1024, 256, 0, stream>>>(Xc, vv, dv, yv, S_out);  // scores
  k_rank<<<128, 256, 0, stream>>>(S_out, tkf);
  k_gather<<<512, 256, 0, stream>>>(X, tkf, Fc);
  k_means_out<<<8, 128, 0, stream>>>(X, tkf, mean, FcMean, FncMean);
}

// Round 8
// 1569.788 us; speedup vs baseline: 1.7832x; 1.7832x over previous
//
#include <hip/hip_runtime.h>

// ---------------------------------------------------------------------------
// CausalityScoreModule: B=8, N=4096, D=128, K=256
// R8 = R6 (passing f32-emulation, bit-exact chains) with k_gram restructured
// for ILP + register reuse. Arithmetic orders preserved EXACTLY:
//   g-chain: d ascending 0..127 (chunks of 16, ascending)
//   acc-chain per (n,j): m = j, j+8, j+16, ... ascending (k-groups ascending)
//   A = fabsf(g / (vn*vm)); PASS1: t2=(dn*A)*dm; acc=fmaf(t2,wm,acc)
//   predux tree over j: (a0+a4),(a1+a5),(a2+a6),(a3+a7) -> (e0+e2)+(e1+e3)
// ---------------------------------------------------------------------------

#define NN 4096
#define DD 128
#define KK 256
#define KT 128          // m-rows per LDS tile
#define NBLK 128        // n-rows per block (Q=4 per thread)
#define LDX 132         // padded LDS row stride (4-bank rotation per row)

__device__ __forceinline__ float f4c(float4 v, int c) {
  return c == 0 ? v.x : c == 1 ? v.y : c == 2 ? v.z : v.w;
}

// --- mean over n (sequential chain per (b,d)) -------------------------------
__global__ __launch_bounds__(128) void k_mean(
    const float* __restrict__ X, float* __restrict__ mean) {
#pragma clang fp contract(off)
  int b = blockIdx.x, d = threadIdx.x;
  const float* p = X + (size_t)b * NN * DD + d;
  float acc = 0.f;
#pragma unroll 8
  for (int n = 0; n < NN; ++n) acc = acc + p[(size_t)n * DD];
  mean[b * DD + d] = acc * (1.0f / 4096.0f);
}

// --- per-row: Xc store, var (seq-d mul-add), y (8-chain fma + predux) -------
__global__ __launch_bounds__(256) void k_rows(
    const float* __restrict__ X, const float* __restrict__ W,
    const float* __restrict__ mean, float* __restrict__ Xc,
    float* __restrict__ vvec, float* __restrict__ yvec) {
#pragma clang fp contract(off)
  __shared__ float wL[DD], mL[DD];
  int t = threadIdx.x;
  int b = blockIdx.x >> 4;
  if (t < DD) { wL[t] = W[t]; mL[t] = mean[b * DD + t]; }
  __syncthreads();
  int rg = blockIdx.x * 256 + t;
  const float* xp = X + (size_t)rg * DD;
  float* xcp = Xc + (size_t)rg * DD;
  float xc[DD];
  float x[DD];
#pragma unroll
  for (int i = 0; i < 32; ++i) {
    float4 v4 = *(const float4*)(xp + i * 4);
    x[i*4] = v4.x; x[i*4+1] = v4.y; x[i*4+2] = v4.z; x[i*4+3] = v4.w;
  }
#pragma unroll
  for (int d = 0; d < DD; ++d) xc[d] = x[d] - mL[d];
#pragma unroll
  for (int i = 0; i < 32; ++i) {
    float4 v4; v4.x = xc[i*4]; v4.y = xc[i*4+1]; v4.z = xc[i*4+2]; v4.w = xc[i*4+3];
    *(float4*)(xcp + i * 4) = v4;
  }
  float vs = 0.f;
#pragma unroll
  for (int d = 0; d < DD; ++d) {
    float p = xc[d] * xc[d];
    vs = vs + p;
  }
  vvec[rg] = sqrtf(vs) + 1e-6f;
  float ay[8] = {0.f,0.f,0.f,0.f,0.f,0.f,0.f,0.f};
#pragma unroll
  for (int d = 0; d < DD; ++d)
    ay[d & 7] = __builtin_fmaf(x[d], wL[d], ay[d & 7]);
  float e0 = ay[0] + ay[4], e1 = ay[1] + ay[5];
  float e2 = ay[2] + ay[6], e3 = ay[3] + ay[7];
  yvec[rg] = (e0 + e2) + (e1 + e3);
}

// --- gram passes (restructured: Q=4 n/thread, 32 ILP chains, dbuf xcn) ------
// Thread (j = t&7, nl = t>>3) owns n = n0 + nl*4 + q (q=0..3) and j-chain
// m = j, j+8, j+16, ... ascending. One phase = one 16-d chunk of the dot.
#define GRAM_PHASE(CUR, NXT, d0v, ncv, rbv)                                  \
  {                                                                          \
    const int nc_ = (ncv);                                                   \
    _Pragma("unroll")                                                        \
    for (int q = 0; q < 4; ++q)                                              \
      _Pragma("unroll")                                                      \
      for (int c = 0; c < 4; ++c)                                            \
        NXT[q][c] = *(const float4*)(xcrow[q] + nc_ * 16 + c * 4);           \
    const int d0_ = (d0v);                                                   \
    const int rb_ = (rbv);                                                   \
    _Pragma("unroll")                                                        \
    for (int k = 0; k < 8; ++k) {                                            \
      float4 m0 = *(const float4*)&Xm[rb_ + k * 8][d0_];                     \
      float4 m1 = *(const float4*)&Xm[rb_ + k * 8][d0_ + 4];                 \
      float4 m2 = *(const float4*)&Xm[rb_ + k * 8][d0_ + 8];                 \
      float4 m3 = *(const float4*)&Xm[rb_ + k * 8][d0_ + 12];                \
      _Pragma("unroll")                                                      \
      for (int dd = 0; dd < 16; ++dd) {                                      \
        float xmv = f4c(dd < 4 ? m0 : dd < 8 ? m1 : dd < 12 ? m2 : m3,       \
                        dd & 3);                                             \
        _Pragma("unroll")                                                    \
        for (int q = 0; q < 4; ++q)                                          \
          g[k][q] = __builtin_fmaf(f4c(CUR[q][dd >> 2], dd & 3), xmv,        \
                                   g[k][q]);                                 \
      }                                                                      \
    }                                                                        \
  }

template <int PASS>
__global__ __launch_bounds__(256, 1) void k_gram(
    const float* __restrict__ Xc, const float* __restrict__ vvec,
    const float* __restrict__ dvec, const float* __restrict__ yvec,
    float* __restrict__ outv) {
#pragma clang fp contract(off)
  __shared__ float Xm[KT][LDX];
  __shared__ float vmL[KT], dmL[KT], wmL[KT];
  __shared__ float red[NBLK][8];
  int bid = blockIdx.x;
  int b = bid & 7;                    // batch -> XCD round robin
  int n0 = (bid >> 3) * NBLK;        // 32 blocks per batch, 256 total
  int t = threadIdx.x;
  int j = t & 7, nl = t >> 3;
  size_t base = (size_t)b * NN * DD;

  const float* xcrow[4];
  float vnq[4], dnq[4], acc[4];
#pragma unroll
  for (int q = 0; q < 4; ++q) {
    int n = n0 + nl * 4 + q;
    xcrow[q] = Xc + base + (size_t)n * DD;
    vnq[q] = vvec[b * NN + n];
    dnq[q] = (PASS == 1) ? dvec[b * NN + n] : 0.f;
    acc[q] = 0.f;
  }

  float4 xa[4][4], xb[4][4];          // xcn chunk double-buffer (16 d each)
#pragma unroll
  for (int q = 0; q < 4; ++q)
#pragma unroll
    for (int c = 0; c < 4; ++c)
      xa[q][c] = *(const float4*)(xcrow[q] + c * 4);   // chunk 0

  for (int mt = 0; mt < 32; ++mt) {
    __syncthreads();                  // prior tile fully consumed
#pragma unroll
    for (int i = 0; i < 16; ++i) {    // stage 128x128 tile
      int e = t + i * 256;
      int r = e >> 5, c4 = e & 31;
      float4 v4 = *(const float4*)(Xc + base + (size_t)(mt * KT + r) * DD + c4 * 4);
      *(float4*)&Xm[r][c4 * 4] = v4;
    }
    if (t < KT) {
      vmL[t] = vvec[b * NN + mt * KT + t];
      if (PASS == 1) {
        dmL[t] = dvec[b * NN + mt * KT + t];
        wmL[t] = yvec[b * NN + mt * KT + t];
      }
    }
    __syncthreads();

    for (int kg = 0; kg < 2; ++kg) {  // k-groups: global k = kg*8 + k
      float g[8][4];
#pragma unroll
      for (int k = 0; k < 8; ++k)
#pragma unroll
        for (int q = 0; q < 4; ++q) g[k][q] = 0.f;

      int rb = kg * 64 + j;           // Xm row base for this (kg, j)
      for (int dc4 = 0; dc4 < 4; ++dc4) {
        GRAM_PHASE(xa, xb, dc4 * 32, 2 * dc4 + 1, rb);
        GRAM_PHASE(xb, xa, dc4 * 32 + 16, (2 * dc4 + 2) & 7, rb);
      }
      // fold: k ascending => m ascending within chain (order preserved)
#pragma unroll
      for (int k = 0; k < 8; ++k) {
        int r = rb + k * 8;
        float vm = vmL[r];
        if (PASS == 0) {
#pragma unroll
          for (int q = 0; q < 4; ++q) {
            float A = fabsf(g[k][q] / (vnq[q] * vm));
            acc[q] = acc[q] + A;
          }
        } else {
          float dm = dmL[r], wm = wmL[r];
#pragma unroll
          for (int q = 0; q < 4; ++q) {
            float A = fabsf(g[k][q] / (vnq[q] * vm));
            float t2 = (dnq[q] * A) * dm;
            acc[q] = __builtin_fmaf(t2, wm, acc[q]);
          }
        }
      }
    }
  }

#pragma unroll
  for (int q = 0; q < 4; ++q) red[nl * 4 + q][j] = acc[q];
  __syncthreads();
  if (t < NBLK) {                     // predux tree (identical to R6)
    float r0 = red[t][0], r1 = red[t][1], r2 = red[t][2], r3 = red[t][3];
    float r4 = red[t][4], r5 = red[t][5], r6 = red[t][6], r7 = red[t][7];
    float e0 = r0 + r4, e1 = r1 + r5, e2 = r2 + r6, e3 = r3 + r7;
    outv[b * NN + n0 + t] = (e0 + e2) + (e1 + e3);
  }
}

// --- d = rowsum ** -0.5 -----------------------------------------------------
__global__ __launch_bounds__(256) void k_d(
    const float* __restrict__ rows, float* __restrict__ dvec) {
#pragma clang fp contract(off)
  int i = blockIdx.x * 256 + threadIdx.x;
  dvec[i] = 1.0f / sqrtf(rows[i]);
}

// --- exact top-256 by rank-counting on f32 S (ties -> smaller index) --------
__global__ __launch_bounds__(256) void k_rank(
    const float* __restrict__ S, int* __restrict__ tkf) {
  __shared__ float sv[NN];
  int b = blockIdx.x >> 4, chunk = blockIdx.x & 15, t = threadIdx.x;
  const float* Sb = S + (size_t)b * NN;
#pragma unroll
  for (int jj = 0; jj < 16; ++jj) sv[t + jj * 256] = Sb[t + jj * 256];
  __syncthreads();
  int n = chunk * 256 + t;
  float s = sv[n];
  int cnt = 0;
  for (int m = 0; m < NN; ++m) {
    float x = sv[m];
    cnt += (x > s) || (x == s && m < n);
  }
  if (cnt < KK) tkf[b * KK + cnt] = n;
}

// --- gather F_c rows --------------------------------------------------------
__global__ __launch_bounds__(256) void k_gather(
    const float* __restrict__ X, const int* __restrict__ tkf,
    float* __restrict__ Fc) {
  int wid = threadIdx.x >> 6, lane = threadIdx.x & 63;
  int rid = blockIdx.x * 4 + wid;
  int b = rid >> 8;
  int idx = tkf[rid];
  ((float2*)Fc)[(size_t)rid * 64 + lane] =
      ((const float2*)X)[((size_t)b * NN + idx) * 64 + lane];
}

// --- means ------------------------------------------------------------------
__global__ __launch_bounds__(128) void k_means_out(
    const float* __restrict__ X, const int* __restrict__ tkf,
    const float* __restrict__ mean, float* __restrict__ FcMean,
    float* __restrict__ FncMean) {
  int b = blockIdx.x, d = threadIdx.x;
  double s = 0.0;
  for (int k = 0; k < KK; ++k) {
    int idx = tkf[b * KK + k];
    s += (double)X[((size_t)b * NN + idx) * DD + d];
  }
  FcMean[b * DD + d] = (float)(s * (1.0 / 256.0));
  double colsum = (double)mean[b * DD + d] * 4096.0;
  FncMean[b * DD + d] = (float)((colsum - s) * (1.0 / 3840.0));
}

// ---------------------------------------------------------------------------
extern "C" void kernel_launch(void* const* d_in, const int* in_sizes, int n_in,
                              void* d_out, int out_size, void* d_ws,
                              size_t ws_size, hipStream_t stream) {
  (void)in_sizes; (void)n_in; (void)out_size; (void)ws_size;
  const float* X = (const float*)d_in[0];
  const float* W = (const float*)d_in[1];
  float* out = (float*)d_out;
  char* ws = (char*)d_ws;

  float* mean = (float*)(ws + 0);                 //   4 KB
  float* Xc   = (float*)(ws + 4096);              //  16 MB
  float* vv   = (float*)(ws + 4096 + 16777216);   // 128 KB
  float* yv   = (float*)(ws + 16912384);          // 128 KB
  float* rows = (float*)(ws + 17043456);          // 128 KB
  float* dv   = (float*)(ws + 17174528);          // 128 KB
  int*   tkf  = (int*)(ws + 17305600);            //   8 KB

  float* S_out   = out;                 // [8,4096]
  float* Fc      = out + 32768;         // [8,256,128]
  float* FcMean  = out + 32768 + 262144;
  float* FncMean = FcMean + 1024;

  k_mean<<<8, 128, 0, stream>>>(X, mean);
  k_rows<<<128, 256, 0, stream>>>(X, W, mean, Xc, vv, yv);
  k_gram<0><<<256, 256, 0, stream>>>(Xc, vv, dv, yv, rows);    // rowsums
  k_d<<<128, 256, 0, stream>>>(rows, dv);
  k_gram<1><<<256, 256, 0, stream>>>(Xc, vv, dv, yv, S_out);   // scores
  k_rank<<<128, 256, 0, stream>>>(S_out, tkf);
  k_gather<<<512, 256, 0, stream>>>(X, tkf, Fc);
  k_means_out<<<8, 128, 0, stream>>>(X, tkf, mean, FcMean, FncMean);
}

// Round 9
// 1405.232 us; speedup vs baseline: 1.9920x; 1.1171x over previous
//
#include <hip/hip_runtime.h>

// ---------------------------------------------------------------------------
// CausalityScoreModule: B=8, N=4096, D=128, K=256
// R9 = R8 (passing, bit-exact f32 emulation) with k_gram at 512 thr/block
// (2 waves/SIMD) and Q=2 rows/thread. Arithmetic orders preserved EXACTLY:
//   g-chain: d ascending 0..127 (16-d chunks ascending, dbuf xa/xb)
//   acc-chain per (n,j): m = j, j+8, ... ascending (kg, k ascending)
//   A = fabsf(g / (vn*vm)); PASS1: t2=(dn*A)*dm; acc=fmaf(t2,wm,acc)
//   predux tree over j: (a0+a4)...(e0+e2)+(e1+e3)
// ---------------------------------------------------------------------------

#define NN 4096
#define DD 128
#define KK 256
#define KT 128          // m-rows per LDS tile
#define NBLK 128        // n-rows per block (Q=2 per thread, 512 threads)
#define LDX 132         // padded LDS row stride

__device__ __forceinline__ float f4c(float4 v, int c) {
  return c == 0 ? v.x : c == 1 ? v.y : c == 2 ? v.z : v.w;
}

// --- mean over n (sequential chain per (b,d)) -------------------------------
__global__ __launch_bounds__(128) void k_mean(
    const float* __restrict__ X, float* __restrict__ mean) {
#pragma clang fp contract(off)
  int b = blockIdx.x, d = threadIdx.x;
  const float* p = X + (size_t)b * NN * DD + d;
  float acc = 0.f;
#pragma unroll 32
  for (int n = 0; n < NN; ++n) acc = acc + p[(size_t)n * DD];
  mean[b * DD + d] = acc * (1.0f / 4096.0f);
}

// --- per-row: Xc store, var (seq-d mul-add), y (8-chain fma + predux) -------
__global__ __launch_bounds__(256) void k_rows(
    const float* __restrict__ X, const float* __restrict__ W,
    const float* __restrict__ mean, float* __restrict__ Xc,
    float* __restrict__ vvec, float* __restrict__ yvec) {
#pragma clang fp contract(off)
  __shared__ float wL[DD], mL[DD];
  int t = threadIdx.x;
  int b = blockIdx.x >> 4;
  if (t < DD) { wL[t] = W[t]; mL[t] = mean[b * DD + t]; }
  __syncthreads();
  int rg = blockIdx.x * 256 + t;
  const float* xp = X + (size_t)rg * DD;
  float* xcp = Xc + (size_t)rg * DD;
  float xc[DD];
  float x[DD];
#pragma unroll
  for (int i = 0; i < 32; ++i) {
    float4 v4 = *(const float4*)(xp + i * 4);
    x[i*4] = v4.x; x[i*4+1] = v4.y; x[i*4+2] = v4.z; x[i*4+3] = v4.w;
  }
#pragma unroll
  for (int d = 0; d < DD; ++d) xc[d] = x[d] - mL[d];
#pragma unroll
  for (int i = 0; i < 32; ++i) {
    float4 v4; v4.x = xc[i*4]; v4.y = xc[i*4+1]; v4.z = xc[i*4+2]; v4.w = xc[i*4+3];
    *(float4*)(xcp + i * 4) = v4;
  }
  float vs = 0.f;
#pragma unroll
  for (int d = 0; d < DD; ++d) {
    float p = xc[d] * xc[d];
    vs = vs + p;
  }
  vvec[rg] = sqrtf(vs) + 1e-6f;
  float ay[8] = {0.f,0.f,0.f,0.f,0.f,0.f,0.f,0.f};
#pragma unroll
  for (int d = 0; d < DD; ++d)
    ay[d & 7] = __builtin_fmaf(x[d], wL[d], ay[d & 7]);
  float e0 = ay[0] + ay[4], e1 = ay[1] + ay[5];
  float e2 = ay[2] + ay[6], e3 = ay[3] + ay[7];
  yvec[rg] = (e0 + e2) + (e1 + e3);
}

// --- gram passes (512 thr: Q=2 n/thread, 16 ILP chains, dbuf xcn) -----------
// Thread (j = t&7, nl = t>>3 in 0..63) owns n = n0 + nl*2 + q (q=0..1) and
// j-chain m = j, j+8, ... ascending. One phase = one 16-d chunk of the dot.
#define GRAM_PHASE(CUR, NXT, d0v, ncv, rbv)                                  \
  {                                                                          \
    const int nc_ = (ncv);                                                   \
    _Pragma("unroll")                                                        \
    for (int q = 0; q < 2; ++q)                                              \
      _Pragma("unroll")                                                      \
      for (int c = 0; c < 4; ++c)                                            \
        NXT[q][c] = *(const float4*)(xcrow[q] + nc_ * 16 + c * 4);           \
    const int d0_ = (d0v);                                                   \
    const int rb_ = (rbv);                                                   \
    _Pragma("unroll")                                                        \
    for (int k = 0; k < 8; ++k) {                                            \
      float4 m0 = *(const float4*)&Xm[rb_ + k * 8][d0_];                     \
      float4 m1 = *(const float4*)&Xm[rb_ + k * 8][d0_ + 4];                 \
      float4 m2 = *(const float4*)&Xm[rb_ + k * 8][d0_ + 8];                 \
      float4 m3 = *(const float4*)&Xm[rb_ + k * 8][d0_ + 12];                \
      _Pragma("unroll")                                                      \
      for (int dd = 0; dd < 16; ++dd) {                                      \
        float xmv = f4c(dd < 4 ? m0 : dd < 8 ? m1 : dd < 12 ? m2 : m3,       \
                        dd & 3);                                             \
        _Pragma("unroll")                                                    \
        for (int q = 0; q < 2; ++q)                                          \
          g[k][q] = __builtin_fmaf(f4c(CUR[q][dd >> 2], dd & 3), xmv,        \
                                   g[k][q]);                                 \
      }                                                                      \
    }                                                                        \
  }

template <int PASS>
__global__ __launch_bounds__(512, 1) void k_gram(
    const float* __restrict__ Xc, const float* __restrict__ vvec,
    const float* __restrict__ dvec, const float* __restrict__ yvec,
    float* __restrict__ outv) {
#pragma clang fp contract(off)
  __shared__ float Xm[KT][LDX];
  __shared__ float vmL[KT], dmL[KT], wmL[KT];
  __shared__ float red[NBLK][8];
  int bid = blockIdx.x;
  int b = bid & 7;                    // batch -> XCD round robin
  int n0 = (bid >> 3) * NBLK;        // 32 blocks per batch, 256 total
  int t = threadIdx.x;
  int j = t & 7, nl = t >> 3;        // nl in 0..63
  size_t base = (size_t)b * NN * DD;

  const float* xcrow[2];
  float vnq[2], dnq[2], acc[2];
#pragma unroll
  for (int q = 0; q < 2; ++q) {
    int n = n0 + nl * 2 + q;
    xcrow[q] = Xc + base + (size_t)n * DD;
    vnq[q] = vvec[b * NN + n];
    dnq[q] = (PASS == 1) ? dvec[b * NN + n] : 0.f;
    acc[q] = 0.f;
  }

  float4 xa[2][4], xb[2][4];          // xcn chunk double-buffer (16 d each)
#pragma unroll
  for (int q = 0; q < 2; ++q)
#pragma unroll
    for (int c = 0; c < 4; ++c)
      xa[q][c] = *(const float4*)(xcrow[q] + c * 4);   // chunk 0

  for (int mt = 0; mt < 32; ++mt) {
    __syncthreads();                  // prior tile fully consumed
#pragma unroll
    for (int i = 0; i < 8; ++i) {     // stage 128x128 tile (512 thr)
      int e = t + i * 512;
      int r = e >> 5, c4 = e & 31;
      float4 v4 = *(const float4*)(Xc + base + (size_t)(mt * KT + r) * DD + c4 * 4);
      *(float4*)&Xm[r][c4 * 4] = v4;
    }
    if (t < KT) {
      vmL[t] = vvec[b * NN + mt * KT + t];
      if (PASS == 1) {
        dmL[t] = dvec[b * NN + mt * KT + t];
        wmL[t] = yvec[b * NN + mt * KT + t];
      }
    }
    __syncthreads();

    for (int kg = 0; kg < 2; ++kg) {  // k-groups: global k = kg*8 + k
      float g[8][2];
#pragma unroll
      for (int k = 0; k < 8; ++k)
#pragma unroll
        for (int q = 0; q < 2; ++q) g[k][q] = 0.f;

      int rb = kg * 64 + j;           // Xm row base for this (kg, j)
      for (int dc4 = 0; dc4 < 4; ++dc4) {
        GRAM_PHASE(xa, xb, dc4 * 32, 2 * dc4 + 1, rb);
        GRAM_PHASE(xb, xa, dc4 * 32 + 16, (2 * dc4 + 2) & 7, rb);
      }
      // fold: k ascending => m ascending within chain (order preserved)
#pragma unroll
      for (int k = 0; k < 8; ++k) {
        int r = rb + k * 8;
        float vm = vmL[r];
        if (PASS == 0) {
#pragma unroll
          for (int q = 0; q < 2; ++q) {
            float A = fabsf(g[k][q] / (vnq[q] * vm));
            acc[q] = acc[q] + A;
          }
        } else {
          float dm = dmL[r], wm = wmL[r];
#pragma unroll
          for (int q = 0; q < 2; ++q) {
            float A = fabsf(g[k][q] / (vnq[q] * vm));
            float t2 = (dnq[q] * A) * dm;
            acc[q] = __builtin_fmaf(t2, wm, acc[q]);
          }
        }
      }
    }
  }

#pragma unroll
  for (int q = 0; q < 2; ++q) red[nl * 2 + q][j] = acc[q];
  __syncthreads();
  if (t < NBLK) {                     // predux tree (identical to R6/R8)
    float r0 = red[t][0], r1 = red[t][1], r2 = red[t][2], r3 = red[t][3];
    float r4 = red[t][4], r5 = red[t][5], r6 = red[t][6], r7 = red[t][7];
    float e0 = r0 + r4, e1 = r1 + r5, e2 = r2 + r6, e3 = r3 + r7;
    outv[b * NN + n0 + t] = (e0 + e2) + (e1 + e3);
  }
}

// --- d = rowsum ** -0.5 -----------------------------------------------------
__global__ __launch_bounds__(256) void k_d(
    const float* __restrict__ rows, float* __restrict__ dvec) {
#pragma clang fp contract(off)
  int i = blockIdx.x * 256 + threadIdx.x;
  dvec[i] = 1.0f / sqrtf(rows[i]);
}

// --- exact top-256 by rank-counting on f32 S (ties -> smaller index) --------
__global__ __launch_bounds__(256) void k_rank(
    const float* __restrict__ S, int* __restrict__ tkf) {
  __shared__ float sv[NN];
  int b = blockIdx.x >> 4, chunk = blockIdx.x & 15, t = threadIdx.x;
  const float* Sb = S + (size_t)b * NN;
#pragma unroll
  for (int jj = 0; jj < 16; ++jj) sv[t + jj * 256] = Sb[t + jj * 256];
  __syncthreads();
  int n = chunk * 256 + t;
  float s = sv[n];
  int cnt = 0;
  for (int m = 0; m < NN; ++m) {
    float x = sv[m];
    cnt += (x > s) || (x == s && m < n);
  }
  if (cnt < KK) tkf[b * KK + cnt] = n;
}

// --- gather F_c rows --------------------------------------------------------
__global__ __launch_bounds__(256) void k_gather(
    const float* __restrict__ X, const int* __restrict__ tkf,
    float* __restrict__ Fc) {
  int wid = threadIdx.x >> 6, lane = threadIdx.x & 63;
  int rid = blockIdx.x * 4 + wid;
  int b = rid >> 8;
  int idx = tkf[rid];
  ((float2*)Fc)[(size_t)rid * 64 + lane] =
      ((const float2*)X)[((size_t)b * NN + idx) * 64 + lane];
}

// --- means ------------------------------------------------------------------
__global__ __launch_bounds__(128) void k_means_out(
    const float* __restrict__ X, const int* __restrict__ tkf,
    const float* __restrict__ mean, float* __restrict__ FcMean,
    float* __restrict__ FncMean) {
  int b = blockIdx.x, d = threadIdx.x;
  double s = 0.0;
  for (int k = 0; k < KK; ++k) {
    int idx = tkf[b * KK + k];
    s += (double)X[((size_t)b * NN + idx) * DD + d];
  }
  FcMean[b * DD + d] = (float)(s * (1.0 / 256.0));
  double colsum = (double)mean[b * DD + d] * 4096.0;
  FncMean[b * DD + d] = (float)((colsum - s) * (1.0 / 3840.0));
}

// ---------------------------------------------------------------------------
extern "C" void kernel_launch(void* const* d_in, const int* in_sizes, int n_in,
                              void* d_out, int out_size, void* d_ws,
                              size_t ws_size, hipStream_t stream) {
  (void)in_sizes; (void)n_in; (void)out_size; (void)ws_size;
  const float* X = (const float*)d_in[0];
  const float* W = (const float*)d_in[1];
  float* out = (float*)d_out;
  char* ws = (char*)d_ws;

  float* mean = (float*)(ws + 0);                 //   4 KB
  float* Xc   = (float*)(ws + 4096);              //  16 MB
  float* vv   = (float*)(ws + 4096 + 16777216);   // 128 KB
  float* yv   = (float*)(ws + 16912384);          // 128 KB
  float* rows = (float*)(ws + 17043456);          // 128 KB
  float* dv   = (float*)(ws + 17174528);          // 128 KB
  int*   tkf  = (int*)(ws + 17305600);            //   8 KB

  float* S_out   = out;                 // [8,4096]
  float* Fc      = out + 32768;         // [8,256,128]
  float* FcMean  = out + 32768 + 262144;
  float* FncMean = FcMean + 1024;

  k_mean<<<8, 128, 0, stream>>>(X, mean);
  k_rows<<<128, 256, 0, stream>>>(X, W, mean, Xc, vv, yv);
  k_gram<0><<<256, 512, 0, stream>>>(Xc, vv, dv, yv, rows);    // rowsums
  k_d<<<128, 256, 0, stream>>>(rows, dv);
  k_gram<1><<<256, 512, 0, stream>>>(Xc, vv, dv, yv, S_out);   // scores
  k_rank<<<128, 256, 0, stream>>>(S_out, tkf);
  k_gather<<<512, 256, 0, stream>>>(X, tkf, Fc);
  k_means_out<<<8, 128, 0, stream>>>(X, tkf, mean, FcMean, FncMean);
}

// Round 10
// 1380.002 us; speedup vs baseline: 2.0284x; 1.0183x over previous
//
#include <hip/hip_runtime.h>

// ---------------------------------------------------------------------------
// CausalityScoreModule: B=8, N=4096, D=128, K=256
// R10 = R9 (passing, bit-exact f32 emulation) + A-matrix materialization:
// pass A stores A=|g/(vn*vm)| (537 MB) while computing rowsums; pass B is a
// memory-bound replay (no g recompute). Chain orders preserved EXACTLY:
//   g-chain: d ascending (16-d chunks, dbuf xa/xb)
//   acc-chain per (n,j): m = j+8K, K ascending  (both passes)
//   PASS B: t2=(dn*A)*dm; acc=fmaf(t2,wm,acc); predux tree over j
// Fallback to the R9 recompute path if ws_size < 555 MB.
// ---------------------------------------------------------------------------

#define NN 4096
#define DD 128
#define KK 256
#define KT 128          // m-rows per LDS tile
#define NBLK 128        // n-rows per block (Q=2 per thread, 512 threads)
#define LDX 132         // padded LDS row stride

__device__ __forceinline__ float f4c(float4 v, int c) {
  return c == 0 ? v.x : c == 1 ? v.y : c == 2 ? v.z : v.w;
}

// --- mean over n (sequential chain per (b,d)) -------------------------------
__global__ __launch_bounds__(128) void k_mean(
    const float* __restrict__ X, float* __restrict__ mean) {
#pragma clang fp contract(off)
  int b = blockIdx.x, d = threadIdx.x;
  const float* p = X + (size_t)b * NN * DD + d;
  float acc = 0.f;
#pragma unroll 32
  for (int n = 0; n < NN; ++n) acc = acc + p[(size_t)n * DD];
  mean[b * DD + d] = acc * (1.0f / 4096.0f);
}

// --- per-row: Xc store, var (seq-d mul-add), y (8-chain fma + predux) -------
__global__ __launch_bounds__(256) void k_rows(
    const float* __restrict__ X, const float* __restrict__ W,
    const float* __restrict__ mean, float* __restrict__ Xc,
    float* __restrict__ vvec, float* __restrict__ yvec) {
#pragma clang fp contract(off)
  __shared__ float wL[DD], mL[DD];
  int t = threadIdx.x;
  int b = blockIdx.x >> 4;
  if (t < DD) { wL[t] = W[t]; mL[t] = mean[b * DD + t]; }
  __syncthreads();
  int rg = blockIdx.x * 256 + t;
  const float* xp = X + (size_t)rg * DD;
  float* xcp = Xc + (size_t)rg * DD;
  float xc[DD];
  float x[DD];
#pragma unroll
  for (int i = 0; i < 32; ++i) {
    float4 v4 = *(const float4*)(xp + i * 4);
    x[i*4] = v4.x; x[i*4+1] = v4.y; x[i*4+2] = v4.z; x[i*4+3] = v4.w;
  }
#pragma unroll
  for (int d = 0; d < DD; ++d) xc[d] = x[d] - mL[d];
#pragma unroll
  for (int i = 0; i < 32; ++i) {
    float4 v4; v4.x = xc[i*4]; v4.y = xc[i*4+1]; v4.z = xc[i*4+2]; v4.w = xc[i*4+3];
    *(float4*)(xcp + i * 4) = v4;
  }
  float vs = 0.f;
#pragma unroll
  for (int d = 0; d < DD; ++d) {
    float p = xc[d] * xc[d];
    vs = vs + p;
  }
  vvec[rg] = sqrtf(vs) + 1e-6f;
  float ay[8] = {0.f,0.f,0.f,0.f,0.f,0.f,0.f,0.f};
#pragma unroll
  for (int d = 0; d < DD; ++d)
    ay[d & 7] = __builtin_fmaf(x[d], wL[d], ay[d & 7]);
  float e0 = ay[0] + ay[4], e1 = ay[1] + ay[5];
  float e2 = ay[2] + ay[6], e3 = ay[3] + ay[7];
  yvec[rg] = (e0 + e2) + (e1 + e3);
}

// --- gram passes (512 thr: Q=2 n/thread, 16 ILP chains, dbuf xcn) -----------
#define GRAM_PHASE(CUR, NXT, d0v, ncv, rbv)                                  \
  {                                                                          \
    const int nc_ = (ncv);                                                   \
    _Pragma("unroll")                                                        \
    for (int q = 0; q < 2; ++q)                                              \
      _Pragma("unroll")                                                      \
      for (int c = 0; c < 4; ++c)                                            \
        NXT[q][c] = *(const float4*)(xcrow[q] + nc_ * 16 + c * 4);           \
    const int d0_ = (d0v);                                                   \
    const int rb_ = (rbv);                                                   \
    _Pragma("unroll")                                                        \
    for (int k = 0; k < 8; ++k) {                                            \
      float4 m0 = *(const float4*)&Xm[rb_ + k * 8][d0_];                     \
      float4 m1 = *(const float4*)&Xm[rb_ + k * 8][d0_ + 4];                 \
      float4 m2 = *(const float4*)&Xm[rb_ + k * 8][d0_ + 8];                 \
      float4 m3 = *(const float4*)&Xm[rb_ + k * 8][d0_ + 12];                \
      _Pragma("unroll")                                                      \
      for (int dd = 0; dd < 16; ++dd) {                                      \
        float xmv = f4c(dd < 4 ? m0 : dd < 8 ? m1 : dd < 12 ? m2 : m3,       \
                        dd & 3);                                             \
        _Pragma("unroll")                                                    \
        for (int q = 0; q < 2; ++q)                                          \
          g[k][q] = __builtin_fmaf(f4c(CUR[q][dd >> 2], dd & 3), xmv,        \
                                   g[k][q]);                                 \
      }                                                                      \
    }                                                                        \
  }

template <int PASS, int STOREA>
__global__ __launch_bounds__(512, 1) void k_gram(
    const float* __restrict__ Xc, const float* __restrict__ vvec,
    const float* __restrict__ dvec, const float* __restrict__ yvec,
    float* __restrict__ outv, float* __restrict__ Aout) {
#pragma clang fp contract(off)
  __shared__ float Xm[KT][LDX];
  __shared__ float vmL[KT], dmL[KT], wmL[KT];
  __shared__ float red[NBLK][8];
  int bid = blockIdx.x;
  int b = bid & 7;                    // batch -> XCD round robin
  int n0 = (bid >> 3) * NBLK;
  int t = threadIdx.x;
  int j = t & 7, nl = t >> 3;        // nl in 0..63
  size_t base = (size_t)b * NN * DD;

  const float* xcrow[2];
  float* aptr[2];
  float vnq[2], dnq[2], acc[2];
#pragma unroll
  for (int q = 0; q < 2; ++q) {
    int n = n0 + nl * 2 + q;
    xcrow[q] = Xc + base + (size_t)n * DD;
    aptr[q] = Aout + ((size_t)(b * NN + n)) * NN;
    vnq[q] = vvec[b * NN + n];
    dnq[q] = (PASS == 1) ? dvec[b * NN + n] : 0.f;
    acc[q] = 0.f;
  }

  float4 xa[2][4], xb[2][4];          // xcn chunk double-buffer
#pragma unroll
  for (int q = 0; q < 2; ++q)
#pragma unroll
    for (int c = 0; c < 4; ++c)
      xa[q][c] = *(const float4*)(xcrow[q] + c * 4);   // chunk 0

  for (int mt = 0; mt < 32; ++mt) {
    __syncthreads();
#pragma unroll
    for (int i = 0; i < 8; ++i) {     // stage 128x128 tile (512 thr)
      int e = t + i * 512;
      int r = e >> 5, c4 = e & 31;
      float4 v4 = *(const float4*)(Xc + base + (size_t)(mt * KT + r) * DD + c4 * 4);
      *(float4*)&Xm[r][c4 * 4] = v4;
    }
    if (t < KT) {
      vmL[t] = vvec[b * NN + mt * KT + t];
      if (PASS == 1) {
        dmL[t] = dvec[b * NN + mt * KT + t];
        wmL[t] = yvec[b * NN + mt * KT + t];
      }
    }
    __syncthreads();

    for (int kg = 0; kg < 2; ++kg) {
      float g[8][2];
#pragma unroll
      for (int k = 0; k < 8; ++k)
#pragma unroll
        for (int q = 0; q < 2; ++q) g[k][q] = 0.f;

      int rb = kg * 64 + j;
      for (int dc4 = 0; dc4 < 4; ++dc4) {
        GRAM_PHASE(xa, xb, dc4 * 32, 2 * dc4 + 1, rb);
        GRAM_PHASE(xb, xa, dc4 * 32 + 16, (2 * dc4 + 2) & 7, rb);
      }
      // fold: k ascending => m ascending within chain (order preserved)
#pragma unroll
      for (int k = 0; k < 8; ++k) {
        int r = rb + k * 8;
        float vm = vmL[r];
        if (PASS == 0) {
#pragma unroll
          for (int q = 0; q < 2; ++q) {
            float A = fabsf(g[k][q] / (vnq[q] * vm));
            acc[q] = acc[q] + A;
            if (STOREA) aptr[q][mt * KT + r] = A;
          }
        } else {
          float dm = dmL[r], wm = wmL[r];
#pragma unroll
          for (int q = 0; q < 2; ++q) {
            float A = fabsf(g[k][q] / (vnq[q] * vm));
            float t2 = (dnq[q] * A) * dm;
            acc[q] = __builtin_fmaf(t2, wm, acc[q]);
          }
        }
      }
    }
  }

#pragma unroll
  for (int q = 0; q < 2; ++q) red[nl * 2 + q][j] = acc[q];
  __syncthreads();
  if (t < NBLK) {                     // predux tree (identical to R6/R8/R9)
    float r0 = red[t][0], r1 = red[t][1], r2 = red[t][2], r3 = red[t][3];
    float r4 = red[t][4], r5 = red[t][5], r6 = red[t][6], r7 = red[t][7];
    float e0 = r0 + r4, e1 = r1 + r5, e2 = r2 + r6, e3 = r3 + r7;
    outv[b * NN + n0 + t] = (e0 + e2) + (e1 + e3);
  }
}

// --- pass B replay: S_n from stored A (memory-bound stream) -----------------
// Thread (j=t&7, nl=t>>3): n = n0+nl; chain m = j+8K, K=0..511 ascending —
// IDENTICAL sequence to the recompute path's (mt,kg,k) lexicographic order.
__global__ __launch_bounds__(256) void k_scoreB(
    const float* __restrict__ A, const float* __restrict__ dvec,
    const float* __restrict__ yvec, float* __restrict__ outv) {
#pragma clang fp contract(off)
  __shared__ float dmL[NN];
  __shared__ float wmL[NN];
  __shared__ float red[32][8];
  int bid = blockIdx.x;               // 1024 blocks
  int b = bid & 7;                    // batch -> XCD round robin
  int n0 = (bid >> 3) * 32;
  int t = threadIdx.x;
  int j = t & 7, nl = t >> 3;         // nl in 0..31
#pragma unroll
  for (int i = 0; i < 4; ++i) {       // stage dm/wm (4096 each)
    int e = t + i * 256;
    ((float4*)dmL)[e] = ((const float4*)(dvec + (size_t)b * NN))[e];
    ((float4*)wmL)[e] = ((const float4*)(yvec + (size_t)b * NN))[e];
  }
  __syncthreads();
  int n = n0 + nl;
  float dn = dmL[n0 + nl - n0 + n0] * 0.f + dvec[(size_t)b * NN + n]; // dn from global (exact same value)
  const float* arow = A + ((size_t)(b * NN + n)) * NN;
  float acc = 0.f;
#pragma unroll 8
  for (int K = 0; K < 512; ++K) {
    int m = j + 8 * K;
    float Av = arow[m];
    float t2 = (dn * Av) * dmL[m];
    acc = __builtin_fmaf(t2, wmL[m], acc);
  }
  red[nl][j] = acc;
  __syncthreads();
  if (t < 32) {                       // predux tree (identical)
    float r0 = red[t][0], r1 = red[t][1], r2 = red[t][2], r3 = red[t][3];
    float r4 = red[t][4], r5 = red[t][5], r6 = red[t][6], r7 = red[t][7];
    float e0 = r0 + r4, e1 = r1 + r5, e2 = r2 + r6, e3 = r3 + r7;
    outv[b * NN + n0 + t] = (e0 + e2) + (e1 + e3);
  }
}

// --- d = rowsum ** -0.5 -----------------------------------------------------
__global__ __launch_bounds__(256) void k_d(
    const float* __restrict__ rows, float* __restrict__ dvec) {
#pragma clang fp contract(off)
  int i = blockIdx.x * 256 + threadIdx.x;
  dvec[i] = 1.0f / sqrtf(rows[i]);
}

// --- exact top-256 by rank-counting on f32 S --------------------------------
__global__ __launch_bounds__(256) void k_rank(
    const float* __restrict__ S, int* __restrict__ tkf) {
  __shared__ float sv[NN];
  int b = blockIdx.x >> 4, chunk = blockIdx.x & 15, t = threadIdx.x;
  const float* Sb = S + (size_t)b * NN;
#pragma unroll
  for (int jj = 0; jj < 16; ++jj) sv[t + jj * 256] = Sb[t + jj * 256];
  __syncthreads();
  int n = chunk * 256 + t;
  float s = sv[n];
  int cnt = 0;
  for (int m = 0; m < NN; ++m) {
    float x = sv[m];
    cnt += (x > s) || (x == s && m < n);
  }
  if (cnt < KK) tkf[b * KK + cnt] = n;
}

// --- gather F_c rows --------------------------------------------------------
__global__ __launch_bounds__(256) void k_gather(
    const float* __restrict__ X, const int* __restrict__ tkf,
    float* __restrict__ Fc) {
  int wid = threadIdx.x >> 6, lane = threadIdx.x & 63;
  int rid = blockIdx.x * 4 + wid;
  int b = rid >> 8;
  int idx = tkf[rid];
  ((float2*)Fc)[(size_t)rid * 64 + lane] =
      ((const float2*)X)[((size_t)b * NN + idx) * 64 + lane];
}

// --- means ------------------------------------------------------------------
__global__ __launch_bounds__(128) void k_means_out(
    const float* __restrict__ X, const int* __restrict__ tkf,
    const float* __restrict__ mean, float* __restrict__ FcMean,
    float* __restrict__ FncMean) {
  int b = blockIdx.x, d = threadIdx.x;
  double s = 0.0;
  for (int k = 0; k < KK; ++k) {
    int idx = tkf[b * KK + k];
    s += (double)X[((size_t)b * NN + idx) * DD + d];
  }
  FcMean[b * DD + d] = (float)(s * (1.0 / 256.0));
  double colsum = (double)mean[b * DD + d] * 4096.0;
  FncMean[b * DD + d] = (float)((colsum - s) * (1.0 / 3840.0));
}

// ---------------------------------------------------------------------------
extern "C" void kernel_launch(void* const* d_in, const int* in_sizes, int n_in,
                              void* d_out, int out_size, void* d_ws,
                              size_t ws_size, hipStream_t stream) {
  (void)in_sizes; (void)n_in; (void)out_size;
  const float* X = (const float*)d_in[0];
  const float* W = (const float*)d_in[1];
  float* out = (float*)d_out;
  char* ws = (char*)d_ws;

  float* mean = (float*)(ws + 0);                 //   4 KB
  float* Xc   = (float*)(ws + 4096);              //  16 MB
  float* vv   = (float*)(ws + 4096 + 16777216);   // 128 KB
  float* yv   = (float*)(ws + 16912384);          // 128 KB
  float* rows = (float*)(ws + 17043456);          // 128 KB
  float* dv   = (float*)(ws + 17174528);          // 128 KB
  int*   tkf  = (int*)(ws + 17305600);            //   8 KB
  float* Amat = (float*)(ws + 17313792);          // 512 MB (optional)
  const size_t NEED = 17313792ull + (size_t)8 * NN * NN * 4;  // ~554.2 MB
  bool bigws = ws_size >= NEED;

  float* S_out   = out;                 // [8,4096]
  float* Fc      = out + 32768;         // [8,256,128]
  float* FcMean  = out + 32768 + 262144;
  float* FncMean = FcMean + 1024;

  k_mean<<<8, 128, 0, stream>>>(X, mean);
  k_rows<<<128, 256, 0, stream>>>(X, W, mean, Xc, vv, yv);
  if (bigws) {
    k_gram<0, 1><<<256, 512, 0, stream>>>(Xc, vv, dv, yv, rows, Amat);
    k_d<<<128, 256, 0, stream>>>(rows, dv);
    k_scoreB<<<1024, 256, 0, stream>>>(Amat, dv, yv, S_out);
  } else {
    k_gram<0, 0><<<256, 512, 0, stream>>>(Xc, vv, dv, yv, rows, Amat);
    k_d<<<128, 256, 0, stream>>>(rows, dv);
    k_gram<1, 0><<<256, 512, 0, stream>>>(Xc, vv, dv, yv, S_out, Amat);
  }
  k_rank<<<128, 256, 0, stream>>>(S_out, tkf);
  k_gather<<<512, 256, 0, stream>>>(X, tkf, Fc);
  k_means_out<<<8, 128, 0, stream>>>(X, tkf, mean, FcMean, FncMean);
}